// Round 2
// baseline (490.080 us; speedup 1.0000x reference)
//
#include <hip/hip_runtime.h>

constexpr int DIM     = 128;
constexpr int BS      = 512;
constexpr int POS_K   = 32;
constexpr int NUM_NEG = 1024;
constexpr float INV_TEMP = 1.0f / 0.07f;

// flat output offsets, in return order
constexpr long long OFF_V2A_POS = 0;
constexpr long long OFF_V2A_NEG = OFF_V2A_POS + BS;                         // 512
constexpr long long OFF_A2V_POS = OFF_V2A_NEG + (long long)BS * NUM_NEG;    // 524800
constexpr long long OFF_A2V_NEG = OFF_A2V_POS + BS;                         // 525312
constexpr long long OFF_VV_POS  = OFF_A2V_NEG + (long long)BS * NUM_NEG;    // 1049600
constexpr long long OFF_VV_NEG  = OFF_VV_POS  + (long long)BS * POS_K;      // 1065984
constexpr long long OFF_AA_POS  = OFF_VV_NEG  + (long long)BS * NUM_NEG;    // 1590272
constexpr long long OFF_AA_NEG  = OFF_AA_POS  + (long long)BS * POS_K;      // 1606656

__device__ __forceinline__ float dot4(const float4 a, const float4 b) {
    return fmaf(a.x, b.x, fmaf(a.y, b.y, fmaf(a.z, b.z, a.w * b.w)));
}

// Merge two per-lane values across xor-mask m: lanes with (li&m)==0 end up
// accumulating `a`, lanes with (li&m)!=0 accumulate `b`. 1 shfl + 2 sel + 1 add.
__device__ __forceinline__ float mrg(float a, float b, int m, bool hi) {
    float keep = hi ? b : a;
    float send = hi ? a : b;
    return keep + __shfl_xor(send, m, 64);
}

// Block layout: gridDim.x = BS*2. Block (b, h): b = bid>>1 handles batch row b,
// half h = bid&1 handles negatives [h*512, h*512+512) and positives [h*16, h*16+16).
// 512 threads = 8 waves; each wave splits into 2 groups of 32 lanes; each group
// processes 2 negative indices (4 gathered rows, 8 dots) per iteration.
__global__ __launch_bounds__(512) void avid_cma_kernel(
    const float* __restrict__ video, const float* __restrict__ audio,
    const float* __restrict__ mem1,  const float* __restrict__ mem2,
    const int* __restrict__ y, const int* __restrict__ pos_idx,
    const int* __restrict__ neg_idx, float* __restrict__ out)
{
    const int tid  = threadIdx.x;
    const int h    = blockIdx.x & 1;
    const int b    = blockIdx.x >> 1;
    const int wave = tid >> 6;
    const int l    = tid & 63;
    const int g    = l >> 5;   // which of the 2 lane-groups
    const int li   = l & 31;   // lane within the 32-lane group

    __shared__ int s_nidx[512];
    __shared__ int s_pidx[16];

    s_nidx[tid] = neg_idx[b * NUM_NEG + h * 512 + tid];
    if (tid < 16) s_pidx[tid] = pos_idx[b * POS_K + h * 16 + tid];

    // ctx slices: lane li owns elements [4*li, 4*li+4) of v and a (raw)
    const float4 vt = *(const float4*)(video + b * DIM + li * 4);
    const float4 at = *(const float4*)(audio + b * DIM + li * 4);

    // norms: butterfly within each 32-lane group (masks <=16 stay in-half)
    float ssv = dot4(vt, vt);
    float ssa = dot4(at, at);
#pragma unroll
    for (int m = 16; m >= 1; m >>= 1) {
        ssv += __shfl_xor(ssv, m, 64);
        ssa += __shfl_xor(ssa, m, 64);
    }
    const float sc_v = INV_TEMP / fmaxf(sqrtf(ssv), 1e-12f);
    const float sc_a = INV_TEMP / fmaxf(sqrtf(ssa), 1e-12f);

    __syncthreads();

    float* o_v2a_neg = out + OFF_V2A_NEG + (long long)b * NUM_NEG + h * 512;
    float* o_a2v_neg = out + OFF_A2V_NEG + (long long)b * NUM_NEG + h * 512;
    float* o_vv_neg  = out + OFF_VV_NEG  + (long long)b * NUM_NEG + h * 512;
    float* o_aa_neg  = out + OFF_AA_NEG  + (long long)b * NUM_NEG + h * 512;

    // routing bits for the merged butterfly
    const bool h16 = (li & 16) != 0;
    const bool h8  = (li & 8)  != 0;
    const bool h4  = (li & 4)  != 0;

    // per-lane store slot: value v = 4*b2 + 2*b3 + b4, stored by lanes li%4==0
    const bool active = (li & 3) == 0;
    const int  b2 = (li >> 2) & 1;   // 0 -> idx A, 1 -> idx B
    const int  b3 = (li >> 3) & 1;   // bank select within route
    const int  b4 = (li >> 4) & 1;   // ctx select within route
    const float st_scale = b4 ? sc_a : sc_v;
    float* st_base = b3 ? (b4 ? o_aa_neg : o_v2a_neg)
                        : (b4 ? o_a2v_neg : o_vv_neg);
    const int st_off = 2 * g + b2;

    // negatives: 16 iterations/wave, 4 rows (8 dots) per group-iteration
    for (int j4 = wave * 4; j4 < 512; j4 += 32) {
        const int idxA = s_nidx[j4 + 2 * g];
        const int idxB = s_nidx[j4 + 2 * g + 1];
        const float4 m1A = *(const float4*)(mem1 + (size_t)idxA * DIM + li * 4);
        const float4 m2A = *(const float4*)(mem2 + (size_t)idxA * DIM + li * 4);
        const float4 m1B = *(const float4*)(mem1 + (size_t)idxB * DIM + li * 4);
        const float4 m2B = *(const float4*)(mem2 + (size_t)idxB * DIM + li * 4);

        const float x0 = dot4(m1A, vt);   // vv_neg[A]
        const float x1 = dot4(m1A, at);   // a2v_neg[A]
        const float x2 = dot4(m2A, vt);   // v2a_neg[A]
        const float x3 = dot4(m2A, at);   // aa_neg[A]
        const float x4 = dot4(m1B, vt);   // vv_neg[B]
        const float x5 = dot4(m1B, at);   // a2v_neg[B]
        const float x6 = dot4(m2B, vt);   // v2a_neg[B]
        const float x7 = dot4(m2B, at);   // aa_neg[B]

        // merged butterfly: 8 values -> 8 lane-slots
        const float r01 = mrg(x0, x1, 16, h16);
        const float r23 = mrg(x2, x3, 16, h16);
        const float r45 = mrg(x4, x5, 16, h16);
        const float r67 = mrg(x6, x7, 16, h16);
        const float s03 = mrg(r01, r23, 8, h8);
        const float s47 = mrg(r45, r67, 8, h8);
        float u = mrg(s03, s47, 4, h4);
        u += __shfl_xor(u, 2, 64);
        u += __shfl_xor(u, 1, 64);

        if (active) st_base[j4 + st_off] = u * st_scale;
    }

    // positives: one iteration/wave (8 waves x 2 rows = 16 per half)
    {
        const int j = wave * 2;
        const int idx = s_pidx[j + g];
        const float4 p1 = *(const float4*)(mem1 + (size_t)idx * DIM + li * 4);
        const float4 p2 = *(const float4*)(mem2 + (size_t)idx * DIM + li * 4);
        const float d1 = dot4(p1, vt);    // pos_v2v_pos
        const float d2 = dot4(p2, at);    // pos_a2a_pos
        float u = mrg(d1, d2, 16, h16);
        u += __shfl_xor(u, 8, 64);
        u += __shfl_xor(u, 4, 64);
        u += __shfl_xor(u, 2, 64);
        u += __shfl_xor(u, 1, 64);
        if (li == 0)
            out[OFF_VV_POS + (long long)b * POS_K + h * 16 + j + g] = u * sc_v;
        if (li == 16)
            out[OFF_AA_POS + (long long)b * POS_K + h * 16 + j + g] = u * sc_a;
    }

    // self scores: half 0, wave 0. group 0: mem2[y]·v ; group 1: mem1[y]·a
    if (h == 0 && wave == 0) {
        const int idx = y[b];
        const float* mp = g ? mem1 : mem2;
        const float4 s = *(const float4*)(mp + (size_t)idx * DIM + li * 4);
        const float4 ct = g ? at : vt;
        float d = dot4(s, ct);
#pragma unroll
        for (int m = 16; m >= 1; m >>= 1) d += __shfl_xor(d, m, 64);
        if (li == 0) {
            if (g == 0) out[OFF_V2A_POS + b] = d * sc_v;   // inst_v2a_pos
            else        out[OFF_A2V_POS + b] = d * sc_a;   // inst_a2v_pos
        }
    }
}

extern "C" void kernel_launch(void* const* d_in, const int* in_sizes, int n_in,
                              void* d_out, int out_size, void* d_ws, size_t ws_size,
                              hipStream_t stream) {
    const float* video   = (const float*)d_in[0];
    const float* audio   = (const float*)d_in[1];
    const float* mem1    = (const float*)d_in[2];
    const float* mem2    = (const float*)d_in[3];
    const int*   y       = (const int*)d_in[4];
    const int*   pos_idx = (const int*)d_in[5];
    const int*   neg_idx = (const int*)d_in[6];
    float*       out     = (float*)d_out;

    avid_cma_kernel<<<dim3(BS * 2), dim3(512), 0, stream>>>(
        video, audio, mem1, mem2, y, pos_idx, neg_idx, out);
}